// Round 20
// baseline (3360.381 us; speedup 1.0000x reference)
//
#include <hip/hip_runtime.h>
#include <hip/hip_bf16.h>
#include <cmath>

#define NP    513
#define NPP   516
#define T_LEN 64
#define JNT   512
#define NITER 30

// d_out scratch (floats): [0..348160) DtD fp32 [640][544] (dead after lnorm1;
// overwritten by fista's Y writes). MUST be zeroed EVERY call (lnorm1 reads
// the full padded buffer; replays would otherwise see stale Y -> garbage L).
#define DTD_STR  544
#define DTD_F    (640 * DTD_STR)
#define Y_ELEMS  1048576

// ws layout (floats)
#define O_DRAWT 0                          // [513][64] f32
#define O_D     32832                      // [64][516] f32 (pad cols zeroed)
#define O_DTY   65856                      // LdtY [32][512][544] f32 (L-scaled, j-major)
#define O_DG1H  8978752                    // Dg1 hi  k-major [68][64][8] bf16
#define O_DG1L  8996160                    // Dg1 lo
#define O_DTGH  9013568                    // Dtg hi  k-major [8][576][8] bf16
#define O_DRH   9032000                    // Draw hi k-major [68][64][8] bf16
#define O_DRL   9049408                    // Draw lo
#define O_LN    9066816                    // lnorm partials + [64]=L, [65]=thr

#define MPAD  576
#define PSTR  544       // LdtY p-stride (global)
#define LDSTR 576       // LDS state row stride (bf16; swizzled)
#define USTRU 72        // U LDS row stride (bf16 elems)
#define LTSTR 548       // LDS ldty row stride (f32)
#define LDSJ  16        // j-columns per block
// per-block LDS: state 2*16*576*2 = 36864 + U 2*16*72*2 = 4608
//              + ldty 16*548*4 = 35072 + Upf 64*18*4 = 4608 -> 81152 B -> 2 blocks/CU
#define LDS_BYTES (2 * LDSJ * LDSTR * 2 + 2 * LDSJ * USTRU * 2 + LDSJ * LTSTR * 4 + 64 * 18 * 4)

typedef short short8 __attribute__((ext_vector_type(8)));
typedef float f32x4  __attribute__((ext_vector_type(4)));

__device__ __forceinline__ unsigned short f2bf(float f) {
    unsigned u = __float_as_uint(f);
    return (unsigned short)((u + 0x7fffu + ((u >> 16) & 1u)) >> 16);
}
__device__ __forceinline__ float bf2f(unsigned short h) {
    return __uint_as_float((unsigned)h << 16);
}
__device__ __forceinline__ void split2(float f, unsigned short& h, unsigned short& l) {
    unsigned short hs = f2bf(f);
    h = hs;
    l = f2bf(f - bf2f(hs));
}
__device__ __forceinline__ unsigned short f2bf_cvt(float f) {
    union { __hip_bfloat16 b; unsigned short u; } cv;
    cv.b = __float2bfloat16(f);
    return cv.u;
}
__device__ __forceinline__ void split2_cvt(float f, unsigned short& h, unsigned short& l) {
    unsigned short hs = f2bf_cvt(f);
    h = hs;
    l = f2bf_cvt(f - bf2f(hs));
}

__global__ void build_D(const float* __restrict__ r, const float* __restrict__ th,
                        float* __restrict__ ws) {
    int p = blockIdx.x;          // 0..512
    int t = threadIdx.x;         // 0..63
    float val;
    if (p == 0) {
        val = 1.0f;
    } else if (p <= 256) {
        int n = p - 1;
        val = powf(r[n], (float)t) * cosf((float)t * th[n]);
    } else {
        int n = p - 257;
        val = powf(r[n], (float)t) * sinf((float)t * th[n]);
    }
    float s = val * val;
    #pragma unroll
    for (int off = 32; off; off >>= 1) s += __shfl_xor(s, off);
    float norm = sqrtf(s);
    ws[O_DRAWT + p * 64 + t] = val;
    ws[O_D + t * NPP + p]    = val / norm;
}

__global__ void dtd_kernel(const float* __restrict__ ws, float* __restrict__ dtd_out) {
    int idx = blockIdx.x * 256 + threadIdx.x;
    if (idx >= NP * NP) return;
    int p = idx / NP, q = idx % NP;
    const float* D = ws + O_D;
    float s = 0.0f;
    #pragma unroll 8
    for (int t = 0; t < T_LEN; t++) s = fmaf(D[t * NPP + p], D[t * NPP + q], s);
    dtd_out[(size_t)p * DTD_STR + q] = s;
}

__global__ __launch_bounds__(256) void lnorm1(const float* __restrict__ dtd_s,
                                              float* __restrict__ ln) {
    __shared__ float sm[256];
    int tid = threadIdx.x;
    size_t base = (size_t)blockIdx.x * 5440;
    float acc = 0.0f;
    for (int i = tid; i < 1360; i += 256) {
        float4 v = *(const float4*)&dtd_s[base + (size_t)i * 4];
        acc += v.x * v.x + v.y * v.y + v.z * v.z + v.w * v.w;
    }
    sm[tid] = acc; __syncthreads();
    for (int off = 128; off; off >>= 1) {
        if (tid < off) sm[tid] += sm[tid + off];
        __syncthreads();
    }
    if (tid == 0) ln[blockIdx.x] = sm[0];
}

__global__ void lnorm2(float* __restrict__ ln) {
    int lane = threadIdx.x;      // 64
    float v = ln[lane];
    #pragma unroll
    for (int off = 32; off; off >>= 1) v += __shfl_xor(v, off);
    if (lane == 0) {
        float L = 1.0f / sqrtf(v);
        ln[64] = L;
        ln[65] = L * 0.1f;
    }
}

// Merged dictionary-operand builder:
//   [0, 34816):        Dg1 hi/lo  (normalized D), k-major [68 q][64 t][8]
//   [34816, 71680):    Dtg hi     (normalized D^T), k-major [8 t][576 p][8]
//   [71680, 106496):   Draw hi/lo (RAW D^T for Y), k-major [68 p][64 t][8]
__global__ void build_ops(const float* __restrict__ ws,
                          unsigned short* __restrict__ Dg1h,
                          unsigned short* __restrict__ Dg1l,
                          unsigned short* __restrict__ Dtgh,
                          unsigned short* __restrict__ Drh,
                          unsigned short* __restrict__ Drl) {
    int idx = blockIdx.x * 256 + threadIdx.x;
    if (idx < 68 * 64 * 8) {
        int i = idx & 7, t = (idx >> 3) & 63, kc8 = idx >> 9;
        int q = kc8 * 8 + i;
        float v = (q < NPP) ? ws[O_D + t * NPP + q] : 0.0f;
        unsigned short h, l;
        split2(v, h, l);
        Dg1h[idx] = h;
        Dg1l[idx] = l;
    } else if (idx < 68 * 64 * 8 + 8 * 576 * 8) {
        int k = idx - 68 * 64 * 8;
        int i = k & 7, p = (k >> 3) % 576, tc = k / 4608;
        int t = tc * 8 + i;
        float v = (p < NP) ? ws[O_D + t * NPP + p] : 0.0f;
        Dtgh[k] = f2bf(v);
    } else {
        int k = idx - (68 * 64 * 8 + 8 * 576 * 8);
        if (k >= 68 * 64 * 8) return;
        int i = k & 7, t = (k >> 3) & 63, kc8 = k >> 9;
        int p = kc8 * 8 + i;
        float v = (p < NP) ? ws[O_DRAWT + p * 64 + t] : 0.0f;
        unsigned short h, l;
        split2(v, h, l);
        Drh[k] = h;
        Drl[k] = l;
    }
}

// LdtY[b][j][p] = L * sum_t D[t,p]*y[b,t,j], p-stride 544
__global__ __launch_bounds__(256) void dty_kernel(const float* __restrict__ y,
                                                  const float* __restrict__ ws,
                                                  const float* __restrict__ lnv,
                                                  float* __restrict__ ldty) {
    __shared__ float As[T_LEN][64];
    __shared__ float Bs[T_LEN][64];
    int tid = threadIdx.x;
    int p0 = blockIdx.x * 64, j0 = blockIdx.y * 64, b = blockIdx.z;
    const float* D = ws + O_D;
    #pragma unroll
    for (int i = 0; i < 4; i++) {
        int lin = i * 256 + tid;
        int kt = lin >> 4, pg = lin & 15;
        float4 v = make_float4(0, 0, 0, 0);
        int pp = p0 + pg * 4;
        if (pp < NPP) v = *(const float4*)&D[kt * NPP + pp];
        *(float4*)&As[kt][pg * 4] = v;
    }
    #pragma unroll
    for (int i = 0; i < 4; i++) {
        int lin = i * 256 + tid;
        int kt = lin >> 4, jg = lin & 15;
        *(float4*)&Bs[kt][jg * 4] =
            *(const float4*)&y[((size_t)b * T_LEN + kt) * JNT + j0 + jg * 4];
    }
    __syncthreads();
    int ty = tid >> 4, tx = tid & 15;
    float acc[4][4] = {};
    #pragma unroll 8
    for (int k = 0; k < T_LEN; k++) {
        float4 a  = *(float4*)&As[k][ty * 4];
        float4 bv = *(float4*)&Bs[k][tx * 4];
        float av[4] = {a.x, a.y, a.z, a.w};
        float bw[4] = {bv.x, bv.y, bv.z, bv.w};
        #pragma unroll
        for (int i2 = 0; i2 < 4; i2++)
            #pragma unroll
            for (int jj = 0; jj < 4; jj++)
                acc[i2][jj] = fmaf(av[i2], bw[jj], acc[i2][jj]);
    }
    float L = lnv[64];
    int p = p0 + ty * 4;
    if (p < PSTR) {
        #pragma unroll
        for (int jj = 0; jj < 4; jj++) {
            int j = j0 + tx * 4 + jj;
            float4 o = make_float4(acc[0][jj] * L, acc[1][jj] * L,
                                   acc[2][jj] * L, acc[3][jj] * L);
            *(float4*)&ldty[((size_t)b * JNT + j) * PSTR + p] = o;
        }
    }
}

// Persistent FISTA, rank-64 factorization. Grid 32x32 = 1024 blocks,
// 512 thr = 8 waves, LDS 81.2 KB -> 2 blocks/CU (4 waves/SIMD).
// R14: L*DtY in LDS. R15: swizzled state + 8-wave GEMM1. R16 hot loop
// (verified 350 us) UNCHANGED. R19: ypred folded in — after the loop,
// final C is repacked into the state LDS and one GEMM1-shaped pass vs
// RAW-D^T (Drh/Drl) writes Y[b][t][jb*16..+16] directly. ln lives in ws.
__global__ __launch_bounds__(512, 4) void fista_persist(
    const unsigned short* __restrict__ Dg1h,
    const unsigned short* __restrict__ Dg1l,
    const unsigned short* __restrict__ Dtgh,
    const unsigned short* __restrict__ Drh,
    const unsigned short* __restrict__ Drl,
    const float* __restrict__ ldty,     // [32][512][544] L-scaled
    const float* __restrict__ lnv,      // ws: [64]=L, [65]=thr
    float* __restrict__ Cg,             // [32][513][512]
    float* __restrict__ Yg)             // [32][64][512]
{
    extern __shared__ unsigned short smv[];
    unsigned short* BhL = smv;                          // state hi [16][576] swz
    unsigned short* BlL = smv + LDSJ * LDSTR;           // state lo
    unsigned short* UhL = smv + 2 * LDSJ * LDSTR;       // U hi [16][72]
    unsigned short* UlL = UhL + LDSJ * USTRU;           // U lo
    float* ldtyL = (float*)(UhL + 2 * LDSJ * USTRU);    // [16][548] f32
    float* Upf   = ldtyL + LDSJ * LTSTR;                // [64][18] f32 partials
    int tid = threadIdx.x;
    int jb = blockIdx.x, b = blockIdx.y;                // jb 0..31
    int lane = tid & 63, w = tid >> 6;                  // w 0..7
    int l15 = lane & 15, l4 = lane >> 4;
    int smaskE = (l15 & 7) << 3;                        // state XOR swizzle (elems)

    {   // zero state (36864 B = 9216 dwords covers hi+lo)
        unsigned* p32 = (unsigned*)smv;
        for (int i = tid; i < LDSJ * LDSTR; i += 512) p32[i] = 0u;
    }
    {   // load this block's L*DtY tile into LDS (once)
        const float* src = ldty + ((size_t)b * JNT + jb * 16) * PSTR;
        for (int i = tid; i < LDSJ * 136; i += 512) {   // 136 float4 per 544-row
            int row = i / 136, c4 = (i % 136) * 4;
            float4 v = *(const float4*)&src[(size_t)row * PSTR + c4];
            *(float4*)&ldtyL[row * LTSTR + c4] = v;
        }
    }

    float L = lnv[64], thr = lnv[65];

    f32x4 ccur[5];    // C_curr (registers, loop-carried)
    f32x4 cprev[5];   // C_prev (registers, loop-carried; LDS holds bf16 copy for GEMM1)
    #pragma unroll
    for (int mi = 0; mi < 5; ++mi) {
        ccur[mi]  = (f32x4){0, 0, 0, 0};
        cprev[mi] = (f32x4){0, 0, 0, 0};
    }
    __syncthreads();

    float t_prev = 1.0f;

    #pragma unroll 1
    for (int it = 0; it < NITER; ++it) {
        float t_next = (1.0f + sqrtf(1.0f + 4.0f * t_prev * t_prev)) * 0.5f;
        float tc = (t_prev - 1.0f) / t_next;
        t_prev = t_next;

        int tf = w & 3, kh = w >> 2;
        f32x4 a1 = (f32x4){0, 0, 0, 0};
        if (it > 0) {
            // ---- GEMM1: all 8 waves; wave w does t-frag tf over K-half kh ----
            int kc0 = (kh == 0) ? 0 : 9;
            int kc1 = (kh == 0) ? 9 : 17;
            int srowb = l15 * LDSTR;
            size_t ntoff = (size_t)(tf * 16 + l15);
            int c0 = ((kc0 * 32 + l4 * 8) ^ smaskE);
            short8 shA = *(const short8*)&BhL[srowb + c0];
            short8 slA = *(const short8*)&BlL[srowb + c0];
            short8 bhA = *(const short8*)&Dg1h[((size_t)(kc0 * 4 + l4) * 64 + ntoff) * 8];
            short8 blA = *(const short8*)&Dg1l[((size_t)(kc0 * 4 + l4) * 64 + ntoff) * 8];
            #pragma unroll 1
            for (int kc = kc0; kc < kc1; ++kc) {
                short8 sh = shA, sl = slA, bh = bhA, bl = blA;
                if (kc + 1 < kc1) {
                    int c = (((kc + 1) * 32 + l4 * 8) ^ smaskE);
                    shA = *(const short8*)&BhL[srowb + c];
                    slA = *(const short8*)&BlL[srowb + c];
                    size_t bo = ((size_t)((kc + 1) * 4 + l4) * 64 + ntoff) * 8;
                    bhA = *(const short8*)&Dg1h[bo];
                    blA = *(const short8*)&Dg1l[bo];
                }
                a1 = __builtin_amdgcn_mfma_f32_16x16x32_bf16(sh, bh, a1, 0, 0, 0);
                a1 = __builtin_amdgcn_mfma_f32_16x16x32_bf16(sl, bh, a1, 0, 0, 0);
                a1 = __builtin_amdgcn_mfma_f32_16x16x32_bf16(sh, bl, a1, 0, 0, 0);
            }
            if (kh == 1) {   // upper half: stash partial
                #pragma unroll
                for (int rr = 0; rr < 4; ++rr)
                    Upf[(tf * 16 + l4 * 4 + rr) * 18 + l15] = a1[rr];
            }
        }
        __syncthreads();   // A: partials visible

        if (it > 0 && kh == 0) {
            // add partner partial, split, store U
            #pragma unroll
            for (int rr = 0; rr < 4; ++rr) {
                float u = a1[rr] + Upf[(tf * 16 + l4 * 4 + rr) * 18 + l15];
                unsigned short h, l;
                split2_cvt(u, h, l);
                int j = l4 * 4 + rr;
                int t = tf * 16 + l15;
                UhL[j * USTRU + t] = h;
                UlL[j * USTRU + t] = l;
            }
        }
        __syncthreads();   // B: U visible

        // ---- GEMM2 + fused elementwise, mi-outer ----
        #pragma unroll
        for (int mi = 0; mi < 5; ++mi) {
            if (mi == 4 && w != 7) continue;      // wave-uniform
            int p = w * 64 + mi * 16 + l4 * 4;
            f32x4 acc = (f32x4){0, 0, 0, 0};
            if (it > 0) {
                short8 dh[2];
                #pragma unroll
                for (int kc2 = 0; kc2 < 2; ++kc2) {
                    size_t o = ((size_t)(kc2 * 4 + l4) * MPAD + w * 64 + mi * 16 + l15) * 8;
                    dh[kc2] = *(const short8*)&Dtgh[o];
                }
                #pragma unroll
                for (int kc2 = 0; kc2 < 2; ++kc2) {
                    int uo = l15 * USTRU + kc2 * 32 + l4 * 8;
                    short8 uh = *(const short8*)&UhL[uo];
                    short8 ul = *(const short8*)&UlL[uo];
                    acc = __builtin_amdgcn_mfma_f32_16x16x32_bf16(dh[kc2], uh, acc, 0, 0, 0);
                    acc = __builtin_amdgcn_mfma_f32_16x16x32_bf16(dh[kc2], ul, acc, 0, 0, 0);
                }
            }
            if (p <= 512) {
                float4 dv = *(const float4*)&ldtyL[l15 * LTSTR + p];
                float dvv[4] = {dv.x, dv.y, dv.z, dv.w};
                int lo = l15 * LDSTR + (p ^ smaskE);
                unsigned short nh[4], nl[4];
                #pragma unroll
                for (int rr = 0; rr < 4; ++rr) {
                    float v  = cprev[mi][rr] - L * acc[rr] + dvv[rr];
                    float a  = fabsf(v) - thr;
                    float st = (a > 0.0f) ? copysignf(a, v) : 0.0f;
                    float po = st + tc * (st - ccur[mi][rr]);
                    ccur[mi][rr]  = st;
                    cprev[mi][rr] = po;
                    split2_cvt(po, nh[rr], nl[rr]);
                }
                *(ushort4*)&BhL[lo] = make_ushort4(nh[0], nh[1], nh[2], nh[3]);
                *(ushort4*)&BlL[lo] = make_ushort4(nl[0], nl[1], nl[2], nl[3]);
            }
        }
        __syncthreads();   // C: state updated
    }

    // final store: C_pred = C_curr -> [b][p][j]
    #pragma unroll
    for (int mi = 0; mi < 5; ++mi) {
        if (mi == 4 && w != 7) continue;
        int pq = w * 64 + mi * 16 + l4 * 4;
        if (pq > 512) continue;
        int j = jb * 16 + l15;
        #pragma unroll
        for (int rr = 0; rr < 4; ++rr) {
            int p = pq + rr;
            if (p < NP) Cg[((size_t)b * NP + p) * JNT + j] = ccur[mi][rr];
        }
    }

    // ---- fused Y: repack final C (ccur) into state LDS, then GEMM vs raw D^T ----
    #pragma unroll
    for (int mi = 0; mi < 5; ++mi) {
        if (mi == 4 && w != 7) continue;
        int p = w * 64 + mi * 16 + l4 * 4;
        if (p <= 512) {
            int lo = l15 * LDSTR + (p ^ smaskE);
            unsigned short nh[4], nl[4];
            #pragma unroll
            for (int rr = 0; rr < 4; ++rr)
                split2_cvt(ccur[mi][rr], nh[rr], nl[rr]);
            *(ushort4*)&BhL[lo] = make_ushort4(nh[0], nh[1], nh[2], nh[3]);
            *(ushort4*)&BlL[lo] = make_ushort4(nl[0], nl[1], nl[2], nl[3]);
        }
    }
    __syncthreads();   // final C visible in state LDS

    {
        int tf = w & 3, kh = w >> 2;
        int kc0 = (kh == 0) ? 0 : 9;
        int kc1 = (kh == 0) ? 9 : 17;
        int srowb = l15 * LDSTR;
        size_t ntoff = (size_t)(tf * 16 + l15);
        f32x4 a1 = (f32x4){0, 0, 0, 0};
        #pragma unroll 1
        for (int kc = kc0; kc < kc1; ++kc) {
            int c = ((kc * 32 + l4 * 8) ^ smaskE);
            short8 sh = *(const short8*)&BhL[srowb + c];
            short8 sl = *(const short8*)&BlL[srowb + c];
            size_t bo = ((size_t)(kc * 4 + l4) * 64 + ntoff) * 8;
            short8 bh = *(const short8*)&Drh[bo];
            short8 bl = *(const short8*)&Drl[bo];
            a1 = __builtin_amdgcn_mfma_f32_16x16x32_bf16(sh, bh, a1, 0, 0, 0);
            a1 = __builtin_amdgcn_mfma_f32_16x16x32_bf16(sl, bh, a1, 0, 0, 0);
            a1 = __builtin_amdgcn_mfma_f32_16x16x32_bf16(sh, bl, a1, 0, 0, 0);
        }
        if (kh == 1) {
            #pragma unroll
            for (int rr = 0; rr < 4; ++rr)
                Upf[(tf * 16 + l4 * 4 + rr) * 18 + l15] = a1[rr];
        }
        __syncthreads();
        if (kh == 0) {
            float y0 = a1[0] + Upf[(tf * 16 + l4 * 4 + 0) * 18 + l15];
            float y1 = a1[1] + Upf[(tf * 16 + l4 * 4 + 1) * 18 + l15];
            float y2 = a1[2] + Upf[(tf * 16 + l4 * 4 + 2) * 18 + l15];
            float y3 = a1[3] + Upf[(tf * 16 + l4 * 4 + 3) * 18 + l15];
            int t = tf * 16 + l15;
            *(float4*)&Yg[((size_t)b * T_LEN + t) * JNT + jb * 16 + l4 * 4] =
                make_float4(y0, y1, y2, y3);
        }
    }
}

extern "C" void kernel_launch(void* const* d_in, const int* in_sizes, int n_in,
                              void* d_out, int out_size, void* d_ws, size_t ws_size,
                              hipStream_t stream) {
    const float* y  = (const float*)d_in[0];
    const float* r  = (const float*)d_in[1];
    const float* th = (const float*)d_in[2];
    float* ws   = (float*)d_ws;
    float* out  = (float*)d_out;
    float* dtd  = out;                 // fp32 scratch in Y region (dead before Y writes)
    float* ln   = ws + O_LN;
    float* Cgo  = out + Y_ELEMS;       // C_pred output region
    unsigned short* Dg1h = (unsigned short*)(ws + O_DG1H);
    unsigned short* Dg1l = (unsigned short*)(ws + O_DG1L);
    unsigned short* Dtgh = (unsigned short*)(ws + O_DTGH);
    unsigned short* Drh  = (unsigned short*)(ws + O_DRH);
    unsigned short* Drl  = (unsigned short*)(ws + O_DRL);
    float* ldty  = ws + O_DTY;

    // DtD scratch must be zero EVERY call: lnorm1 sums the full padded
    // [640][544] buffer and replays would otherwise read stale Y (R19 bug).
    hipMemsetAsync(out,      0, (size_t)DTD_F * 4, stream);
    hipMemsetAsync(ws + O_D, 0, (size_t)(T_LEN * NPP) * 4, stream);

    build_D<<<NP, 64, 0, stream>>>(r, th, ws);
    dtd_kernel<<<(NP * NP + 255) / 256, 256, 0, stream>>>(ws, dtd);
    lnorm1<<<64, 256, 0, stream>>>(dtd, ln);
    lnorm2<<<1, 64, 0, stream>>>(ln);
    dty_kernel<<<dim3(9, 8, 32), 256, 0, stream>>>(y, ws, ln, ldty);
    build_ops<<<(2 * 68 * 64 * 8 + 8 * 576 * 8 + 255) / 256, 256, 0, stream>>>(
        ws, Dg1h, Dg1l, Dtgh, Drh, Drl);

    hipFuncSetAttribute((const void*)fista_persist,
                        hipFuncAttributeMaxDynamicSharedMemorySize, LDS_BYTES);
    fista_persist<<<dim3(32, 32), 512, LDS_BYTES, stream>>>(Dg1h, Dg1l, Dtgh,
                                                            Drh, Drl, ldty, ln,
                                                            Cgo, out);
}

// Round 21
// 399.622 us; speedup vs baseline: 8.4089x; 8.4089x over previous
//
#include <hip/hip_runtime.h>
#include <hip/hip_bf16.h>
#include <cmath>

#define NP    513
#define NPP   516
#define T_LEN 64
#define JNT   512
#define NITER 30

// d_out scratch (floats): [0..348160) DtD fp32 [640][544]; [348160..348226) lnorm.
// Both overwritten later by ypred (Y region = 1,048,576 floats).
#define DTD_STR  544
#define DTD_F    (640 * DTD_STR)
#define LN_OFF   DTD_F
#define Y_ELEMS  1048576

// ws layout (floats)
#define O_DRAWT 0                          // [513][64] f32
#define O_D     32832                      // [64][516] f32 (pad cols zeroed)
#define O_DTY   65856                      // LdtY [32][512][544] f32 (L-scaled, j-major)
#define O_DG1H  8978752                    // Dg1 hi  k-major [68][64][8] bf16
#define O_DG1L  8996160                    // Dg1 lo
#define O_DTGH  9013568                    // Dtg hi  k-major [8][576][8] bf16

#define MPAD  576
#define PSTR  544       // LdtY p-stride (global)
#define LDSTR 576       // LDS state row stride (bf16; swizzled)
#define USTRU 72        // U LDS row stride (bf16 elems)
#define LTSTR 548       // LDS ldty row stride (f32)
#define LDSJ  16        // j-columns per block
// per-block LDS: state 2*16*576*2 = 36864 + U 2*16*72*2 = 4608
//              + ldty 16*548*4 = 35072 + Upf 64*18*4 = 4608 -> 81152 B -> 2 blocks/CU
#define LDS_BYTES (2 * LDSJ * LDSTR * 2 + 2 * LDSJ * USTRU * 2 + LDSJ * LTSTR * 4 + 64 * 18 * 4)

typedef short short8 __attribute__((ext_vector_type(8)));
typedef float f32x4  __attribute__((ext_vector_type(4)));

__device__ __forceinline__ unsigned short f2bf(float f) {
    unsigned u = __float_as_uint(f);
    return (unsigned short)((u + 0x7fffu + ((u >> 16) & 1u)) >> 16);
}
__device__ __forceinline__ float bf2f(unsigned short h) {
    return __uint_as_float((unsigned)h << 16);
}
__device__ __forceinline__ void split2(float f, unsigned short& h, unsigned short& l) {
    unsigned short hs = f2bf(f);
    h = hs;
    l = f2bf(f - bf2f(hs));
}
__device__ __forceinline__ unsigned short f2bf_cvt(float f) {
    union { __hip_bfloat16 b; unsigned short u; } cv;
    cv.b = __float2bfloat16(f);
    return cv.u;
}
__device__ __forceinline__ void split2_cvt(float f, unsigned short& h, unsigned short& l) {
    unsigned short hs = f2bf_cvt(f);
    h = hs;
    l = f2bf_cvt(f - bf2f(hs));
}

__global__ void build_D(const float* __restrict__ r, const float* __restrict__ th,
                        float* __restrict__ ws) {
    int p = blockIdx.x;          // 0..512
    int t = threadIdx.x;         // 0..63
    float val;
    if (p == 0) {
        val = 1.0f;
    } else if (p <= 256) {
        int n = p - 1;
        val = powf(r[n], (float)t) * cosf((float)t * th[n]);
    } else {
        int n = p - 257;
        val = powf(r[n], (float)t) * sinf((float)t * th[n]);
    }
    float s = val * val;
    #pragma unroll
    for (int off = 32; off; off >>= 1) s += __shfl_xor(s, off);
    float norm = sqrtf(s);
    ws[O_DRAWT + p * 64 + t] = val;
    ws[O_D + t * NPP + p]    = val / norm;
}

__global__ void dtd_kernel(const float* __restrict__ ws, float* __restrict__ dtd_out) {
    int idx = blockIdx.x * 256 + threadIdx.x;
    if (idx >= NP * NP) return;
    int p = idx / NP, q = idx % NP;
    const float* D = ws + O_D;
    float s = 0.0f;
    #pragma unroll 8
    for (int t = 0; t < T_LEN; t++) s = fmaf(D[t * NPP + p], D[t * NPP + q], s);
    dtd_out[(size_t)p * DTD_STR + q] = s;
}

__global__ __launch_bounds__(256) void lnorm1(const float* __restrict__ dtd_s,
                                              float* __restrict__ ln) {
    __shared__ float sm[256];
    int tid = threadIdx.x;
    size_t base = (size_t)blockIdx.x * 5440;
    float acc = 0.0f;
    for (int i = tid; i < 1360; i += 256) {
        float4 v = *(const float4*)&dtd_s[base + (size_t)i * 4];
        acc += v.x * v.x + v.y * v.y + v.z * v.z + v.w * v.w;
    }
    sm[tid] = acc; __syncthreads();
    for (int off = 128; off; off >>= 1) {
        if (tid < off) sm[tid] += sm[tid + off];
        __syncthreads();
    }
    if (tid == 0) ln[blockIdx.x] = sm[0];
}

__global__ void lnorm2(float* __restrict__ ln) {
    int lane = threadIdx.x;      // 64
    float v = ln[lane];
    #pragma unroll
    for (int off = 32; off; off >>= 1) v += __shfl_xor(v, off);
    if (lane == 0) {
        float L = 1.0f / sqrtf(v);
        ln[64] = L;
        ln[65] = L * 0.1f;
    }
}

// Merged dictionary-operand builder:
//   idx < 34816:  Dg1 hi/lo, k-major [68 qchunk][64 t][8] (q >= 513 zero)
//   else:         Dtg hi only, k-major [8 tchunk][576 p][8] (p >= 513 zero)
__global__ void build_ops(const float* __restrict__ ws,
                          unsigned short* __restrict__ Dg1h,
                          unsigned short* __restrict__ Dg1l,
                          unsigned short* __restrict__ Dtgh) {
    int idx = blockIdx.x * 256 + threadIdx.x;
    if (idx < 68 * 64 * 8) {
        int i = idx & 7, t = (idx >> 3) & 63, kc8 = idx >> 9;
        int q = kc8 * 8 + i;
        float v = (q < NPP) ? ws[O_D + t * NPP + q] : 0.0f;
        unsigned short h, l;
        split2(v, h, l);
        Dg1h[idx] = h;
        Dg1l[idx] = l;
    } else {
        int k = idx - 68 * 64 * 8;
        if (k >= 8 * 576 * 8) return;
        int i = k & 7, p = (k >> 3) % 576, tc = k / 4608;
        int t = tc * 8 + i;
        float v = (p < NP) ? ws[O_D + t * NPP + p] : 0.0f;
        Dtgh[k] = f2bf(v);
    }
}

// LdtY[b][j][p] = L * sum_t D[t,p]*y[b,t,j], p-stride 544
__global__ __launch_bounds__(256) void dty_kernel(const float* __restrict__ y,
                                                  const float* __restrict__ ws,
                                                  const float* __restrict__ lnv,
                                                  float* __restrict__ ldty) {
    __shared__ float As[T_LEN][64];
    __shared__ float Bs[T_LEN][64];
    int tid = threadIdx.x;
    int p0 = blockIdx.x * 64, j0 = blockIdx.y * 64, b = blockIdx.z;
    const float* D = ws + O_D;
    #pragma unroll
    for (int i = 0; i < 4; i++) {
        int lin = i * 256 + tid;
        int kt = lin >> 4, pg = lin & 15;
        float4 v = make_float4(0, 0, 0, 0);
        int pp = p0 + pg * 4;
        if (pp < NPP) v = *(const float4*)&D[kt * NPP + pp];
        *(float4*)&As[kt][pg * 4] = v;
    }
    #pragma unroll
    for (int i = 0; i < 4; i++) {
        int lin = i * 256 + tid;
        int kt = lin >> 4, jg = lin & 15;
        *(float4*)&Bs[kt][jg * 4] =
            *(const float4*)&y[((size_t)b * T_LEN + kt) * JNT + j0 + jg * 4];
    }
    __syncthreads();
    int ty = tid >> 4, tx = tid & 15;
    float acc[4][4] = {};
    #pragma unroll 8
    for (int k = 0; k < T_LEN; k++) {
        float4 a  = *(float4*)&As[k][ty * 4];
        float4 bv = *(float4*)&Bs[k][tx * 4];
        float av[4] = {a.x, a.y, a.z, a.w};
        float bw[4] = {bv.x, bv.y, bv.z, bv.w};
        #pragma unroll
        for (int i2 = 0; i2 < 4; i2++)
            #pragma unroll
            for (int jj = 0; jj < 4; jj++)
                acc[i2][jj] = fmaf(av[i2], bw[jj], acc[i2][jj]);
    }
    float L = lnv[64];
    int p = p0 + ty * 4;
    if (p < PSTR) {
        #pragma unroll
        for (int jj = 0; jj < 4; jj++) {
            int j = j0 + tx * 4 + jj;
            float4 o = make_float4(acc[0][jj] * L, acc[1][jj] * L,
                                   acc[2][jj] * L, acc[3][jj] * L);
            *(float4*)&ldty[((size_t)b * JNT + j) * PSTR + p] = o;
        }
    }
}

// Persistent FISTA, rank-64 factorization. Grid 32x32 = 1024 blocks,
// 512 thr = 8 waves, LDS 81.2 KB -> 2 blocks/CU (4 waves/SIMD).
// R14: L*DtY in LDS (no remat possible). R15: swizzled state + 8-wave GEMM1.
// R16 (this exact body, verified 350 us): C_prev/C_curr in registers,
// GEMM2 2-product dh*(uh+ul). R17/R19/R20 additions all REVERTED — each
// perturbed the allocator into loop-scratch spills (R20: 19 GB/dispatch).
__global__ __launch_bounds__(512, 4) void fista_persist(
    const unsigned short* __restrict__ Dg1h,
    const unsigned short* __restrict__ Dg1l,
    const unsigned short* __restrict__ Dtgh,
    const float* __restrict__ ldty,     // [32][512][544] L-scaled
    const float* __restrict__ lnv,      // [64]=L, [65]=thr
    float* __restrict__ Cg)             // [32][513][512]
{
    extern __shared__ unsigned short smv[];
    unsigned short* BhL = smv;                          // state hi [16][576] swz
    unsigned short* BlL = smv + LDSJ * LDSTR;           // state lo
    unsigned short* UhL = smv + 2 * LDSJ * LDSTR;       // U hi [16][72]
    unsigned short* UlL = UhL + LDSJ * USTRU;           // U lo
    float* ldtyL = (float*)(UhL + 2 * LDSJ * USTRU);    // [16][548] f32
    float* Upf   = ldtyL + LDSJ * LTSTR;                // [64][18] f32 partials
    int tid = threadIdx.x;
    int jb = blockIdx.x, b = blockIdx.y;                // jb 0..31
    int lane = tid & 63, w = tid >> 6;                  // w 0..7
    int l15 = lane & 15, l4 = lane >> 4;
    int smaskE = (l15 & 7) << 3;                        // state XOR swizzle (elems)

    {   // zero state (36864 B = 9216 dwords covers hi+lo)
        unsigned* p32 = (unsigned*)smv;
        for (int i = tid; i < LDSJ * LDSTR; i += 512) p32[i] = 0u;
    }
    {   // load this block's L*DtY tile into LDS (once)
        const float* src = ldty + ((size_t)b * JNT + jb * 16) * PSTR;
        for (int i = tid; i < LDSJ * 136; i += 512) {   // 136 float4 per 544-row
            int row = i / 136, c4 = (i % 136) * 4;
            float4 v = *(const float4*)&src[(size_t)row * PSTR + c4];
            *(float4*)&ldtyL[row * LTSTR + c4] = v;
        }
    }

    float L = lnv[64], thr = lnv[65];

    f32x4 ccur[5];    // C_curr (registers, loop-carried)
    f32x4 cprev[5];   // C_prev (registers, loop-carried; LDS holds bf16 copy for GEMM1)
    #pragma unroll
    for (int mi = 0; mi < 5; ++mi) {
        ccur[mi]  = (f32x4){0, 0, 0, 0};
        cprev[mi] = (f32x4){0, 0, 0, 0};
    }
    __syncthreads();

    float t_prev = 1.0f;

    #pragma unroll 1
    for (int it = 0; it < NITER; ++it) {
        float t_next = (1.0f + sqrtf(1.0f + 4.0f * t_prev * t_prev)) * 0.5f;
        float tc = (t_prev - 1.0f) / t_next;
        t_prev = t_next;

        int tf = w & 3, kh = w >> 2;
        f32x4 a1 = (f32x4){0, 0, 0, 0};
        if (it > 0) {
            // ---- GEMM1: all 8 waves; wave w does t-frag tf over K-half kh ----
            int kc0 = (kh == 0) ? 0 : 9;
            int kc1 = (kh == 0) ? 9 : 17;
            int srowb = l15 * LDSTR;
            size_t ntoff = (size_t)(tf * 16 + l15);
            int c0 = ((kc0 * 32 + l4 * 8) ^ smaskE);
            short8 shA = *(const short8*)&BhL[srowb + c0];
            short8 slA = *(const short8*)&BlL[srowb + c0];
            short8 bhA = *(const short8*)&Dg1h[((size_t)(kc0 * 4 + l4) * 64 + ntoff) * 8];
            short8 blA = *(const short8*)&Dg1l[((size_t)(kc0 * 4 + l4) * 64 + ntoff) * 8];
            #pragma unroll 1
            for (int kc = kc0; kc < kc1; ++kc) {
                short8 sh = shA, sl = slA, bh = bhA, bl = blA;
                if (kc + 1 < kc1) {
                    int c = (((kc + 1) * 32 + l4 * 8) ^ smaskE);
                    shA = *(const short8*)&BhL[srowb + c];
                    slA = *(const short8*)&BlL[srowb + c];
                    size_t bo = ((size_t)((kc + 1) * 4 + l4) * 64 + ntoff) * 8;
                    bhA = *(const short8*)&Dg1h[bo];
                    blA = *(const short8*)&Dg1l[bo];
                }
                a1 = __builtin_amdgcn_mfma_f32_16x16x32_bf16(sh, bh, a1, 0, 0, 0);
                a1 = __builtin_amdgcn_mfma_f32_16x16x32_bf16(sl, bh, a1, 0, 0, 0);
                a1 = __builtin_amdgcn_mfma_f32_16x16x32_bf16(sh, bl, a1, 0, 0, 0);
            }
            if (kh == 1) {   // upper half: stash partial
                #pragma unroll
                for (int rr = 0; rr < 4; ++rr)
                    Upf[(tf * 16 + l4 * 4 + rr) * 18 + l15] = a1[rr];
            }
        }
        __syncthreads();   // A: partials visible

        if (it > 0 && kh == 0) {
            // add partner partial, split, store U
            #pragma unroll
            for (int rr = 0; rr < 4; ++rr) {
                float u = a1[rr] + Upf[(tf * 16 + l4 * 4 + rr) * 18 + l15];
                unsigned short h, l;
                split2_cvt(u, h, l);
                int j = l4 * 4 + rr;
                int t = tf * 16 + l15;
                UhL[j * USTRU + t] = h;
                UlL[j * USTRU + t] = l;
            }
        }
        __syncthreads();   // B: U visible

        // ---- GEMM2 + fused elementwise, mi-outer ----
        #pragma unroll
        for (int mi = 0; mi < 5; ++mi) {
            if (mi == 4 && w != 7) continue;      // wave-uniform
            int p = w * 64 + mi * 16 + l4 * 4;
            f32x4 acc = (f32x4){0, 0, 0, 0};
            if (it > 0) {
                short8 dh[2];
                #pragma unroll
                for (int kc2 = 0; kc2 < 2; ++kc2) {
                    size_t o = ((size_t)(kc2 * 4 + l4) * MPAD + w * 64 + mi * 16 + l15) * 8;
                    dh[kc2] = *(const short8*)&Dtgh[o];
                }
                #pragma unroll
                for (int kc2 = 0; kc2 < 2; ++kc2) {
                    int uo = l15 * USTRU + kc2 * 32 + l4 * 8;
                    short8 uh = *(const short8*)&UhL[uo];
                    short8 ul = *(const short8*)&UlL[uo];
                    acc = __builtin_amdgcn_mfma_f32_16x16x32_bf16(dh[kc2], uh, acc, 0, 0, 0);
                    acc = __builtin_amdgcn_mfma_f32_16x16x32_bf16(dh[kc2], ul, acc, 0, 0, 0);
                }
            }
            if (p <= 512) {
                float4 dv = *(const float4*)&ldtyL[l15 * LTSTR + p];
                float dvv[4] = {dv.x, dv.y, dv.z, dv.w};
                int lo = l15 * LDSTR + (p ^ smaskE);
                unsigned short nh[4], nl[4];
                #pragma unroll
                for (int rr = 0; rr < 4; ++rr) {
                    float v  = cprev[mi][rr] - L * acc[rr] + dvv[rr];
                    float a  = fabsf(v) - thr;
                    float st = (a > 0.0f) ? copysignf(a, v) : 0.0f;
                    float po = st + tc * (st - ccur[mi][rr]);
                    ccur[mi][rr]  = st;
                    cprev[mi][rr] = po;
                    split2_cvt(po, nh[rr], nl[rr]);
                }
                *(ushort4*)&BhL[lo] = make_ushort4(nh[0], nh[1], nh[2], nh[3]);
                *(ushort4*)&BlL[lo] = make_ushort4(nl[0], nl[1], nl[2], nl[3]);
            }
        }
        __syncthreads();   // C: state updated
    }

    // final store: C_pred = C_curr -> [b][p][j]
    #pragma unroll
    for (int mi = 0; mi < 5; ++mi) {
        if (mi == 4 && w != 7) continue;
        int pq = w * 64 + mi * 16 + l4 * 4;
        if (pq > 512) continue;
        int j = jb * 16 + l15;
        #pragma unroll
        for (int rr = 0; rr < 4; ++rr) {
            int p = pq + rr;
            if (p < NP) Cg[((size_t)b * NP + p) * JNT + j] = ccur[mi][rr];
        }
    }
}

// Y[b,t,j] = sum_p D_raw[t,p] * C[b,p,j]
__global__ __launch_bounds__(256) void ypred_kernel(const float* __restrict__ ws_c,
                                                    const float* __restrict__ C,
                                                    float* __restrict__ Y) {
    __shared__ float As[32][64];
    __shared__ float Bs[32][64];
    int tid = threadIdx.x;
    int j0 = blockIdx.x * 64, b = blockIdx.y;
    const float* DrawT = ws_c + O_DRAWT;
    float acc[4][4] = {};
    int ty = tid >> 4, tx = tid & 15;
    for (int kc = 0; kc < 17; kc++) {
        int p0 = kc * 32;
        #pragma unroll
        for (int i = 0; i < 2; i++) {
            int lin = i * 256 + tid;
            int kp = lin >> 4, tg = lin & 15;
            float4 v = make_float4(0, 0, 0, 0);
            int p = p0 + kp;
            if (p < NP) v = *(const float4*)&DrawT[(size_t)p * 64 + tg * 4];
            *(float4*)&As[kp][tg * 4] = v;
        }
        #pragma unroll
        for (int i = 0; i < 2; i++) {
            int lin = i * 256 + tid;
            int kp = lin >> 4, jg = lin & 15;
            float4 v = make_float4(0, 0, 0, 0);
            int p = p0 + kp;
            if (p < NP) v = *(const float4*)&C[((size_t)b * NP + p) * JNT + j0 + jg * 4];
            *(float4*)&Bs[kp][jg * 4] = v;
        }
        __syncthreads();
        #pragma unroll
        for (int k = 0; k < 32; k++) {
            float4 a  = *(float4*)&As[k][ty * 4];
            float4 bv = *(float4*)&Bs[k][tx * 4];
            float av[4] = {a.x, a.y, a.z, a.w};
            float bw[4] = {bv.x, bv.y, bv.z, bv.w};
            #pragma unroll
            for (int i2 = 0; i2 < 4; i2++)
                #pragma unroll
                for (int jj = 0; jj < 4; jj++)
                    acc[i2][jj] = fmaf(av[i2], bw[jj], acc[i2][jj]);
        }
        __syncthreads();
    }
    #pragma unroll
    for (int i2 = 0; i2 < 4; i2++) {
        int t = ty * 4 + i2;
        size_t base = ((size_t)b * T_LEN + t) * JNT + j0 + tx * 4;
        *(float4*)&Y[base] = make_float4(acc[i2][0], acc[i2][1], acc[i2][2], acc[i2][3]);
    }
}

extern "C" void kernel_launch(void* const* d_in, const int* in_sizes, int n_in,
                              void* d_out, int out_size, void* d_ws, size_t ws_size,
                              hipStream_t stream) {
    const float* y  = (const float*)d_in[0];
    const float* r  = (const float*)d_in[1];
    const float* th = (const float*)d_in[2];
    float* ws   = (float*)d_ws;
    float* out  = (float*)d_out;
    float* dtd  = out;                 // fp32 scratch in Y region
    float* ln   = out + LN_OFF;
    float* Cgo  = out + Y_ELEMS;       // C_pred output region
    unsigned short* Dg1h = (unsigned short*)(ws + O_DG1H);
    unsigned short* Dg1l = (unsigned short*)(ws + O_DG1L);
    unsigned short* Dtgh = (unsigned short*)(ws + O_DTGH);
    float* ldty  = ws + O_DTY;

    hipMemsetAsync(out,      0, (size_t)(DTD_F + 68) * 4, stream);
    hipMemsetAsync(ws + O_D, 0, (size_t)(T_LEN * NPP) * 4, stream);

    build_D<<<NP, 64, 0, stream>>>(r, th, ws);
    dtd_kernel<<<(NP * NP + 255) / 256, 256, 0, stream>>>(ws, dtd);
    lnorm1<<<64, 256, 0, stream>>>(dtd, ln);
    lnorm2<<<1, 64, 0, stream>>>(ln);
    dty_kernel<<<dim3(9, 8, 32), 256, 0, stream>>>(y, ws, ln, ldty);
    build_ops<<<(68 * 64 * 8 + 8 * 576 * 8 + 255) / 256, 256, 0, stream>>>(
        ws, Dg1h, Dg1l, Dtgh);

    hipFuncSetAttribute((const void*)fista_persist,
                        hipFuncAttributeMaxDynamicSharedMemorySize, LDS_BYTES);
    fista_persist<<<dim3(32, 32), 512, LDS_BYTES, stream>>>(Dg1h, Dg1l, Dtgh,
                                                            ldty, ln, Cgo);

    ypred_kernel<<<dim3(8, 32), 256, 0, stream>>>(ws, Cgo, out);
}